// Round 14
// baseline (761.684 us; speedup 1.0000x reference)
//
#include <hip/hip_runtime.h>
#include <hip/hip_bf16.h>

#define BATCH 65536
#define DK 512
#define DV 512
#define DH 64
#define BMR 16          // rows per block; wave covers cols [wave*128, wave*128+128)

typedef __attribute__((ext_vector_type(8))) short bf16x8;
typedef __attribute__((ext_vector_type(4))) float f32x4;

// FRAGMENT-ORDERED bf16 weight images (one coalesced 1KB load per wave-frag):
//   shorts [0, 32768):       W1F  (4 tiles x 16 kk x 64 lanes x 8)
//   shorts [32768, 65536):   W2F  (32 tiles x 2 kh x 64 lanes x 8)
//   shorts [65536, 327680):  WpF  (32 tiles x 16 kk x 64 lanes x 8)
__device__ __align__(16) short g_wb[327680];

__device__ __forceinline__ short f2bf(float f) {
    union { __hip_bfloat16 h; short s; } u;
    u.h = __float2bfloat16(f);
    return u.s;
}

__device__ __forceinline__ bf16x8 pack8(float4 a, float4 b) {
    bf16x8 r;
    r[0] = f2bf(a.x); r[1] = f2bf(a.y); r[2] = f2bf(a.z); r[3] = f2bf(a.w);
    r[4] = f2bf(b.x); r[5] = f2bf(b.y); r[6] = f2bf(b.z); r[7] = f2bf(b.w);
    return r;
}

__global__ __launch_bounds__(256) void conv_weights(
    const float* __restrict__ W1, const float* __restrict__ W2,
    const float* __restrict__ Wp)
{
    int f = blockIdx.x * 256 + threadIdx.x;
    int lane = f & 63;
    const float* src; int stride, row, col;
    if (f < 4096) {                    // W1F
        int t = f >> 10, kk = (f >> 6) & 15;
        src = W1; stride = DK;
        row = t * 16 + (lane & 15); col = kk * 32 + (lane >> 4) * 8;
    } else if (f < 8192) {             // W2F
        int g = f - 4096; int t = g >> 7, kh = (g >> 6) & 1;
        src = W2; stride = DH;
        row = t * 16 + (lane & 15); col = kh * 32 + (lane >> 4) * 8;
    } else {                           // WpF
        int g = f - 8192; int t = g >> 10, kk = (g >> 6) & 15;
        src = Wp; stride = DK;
        row = t * 16 + (lane & 15); col = kk * 32 + (lane >> 4) * 8;
    }
    const float* p = src + (long)row * stride + col;
    float4 a = *reinterpret_cast<const float4*>(p);
    float4 b = *reinterpret_cast<const float4*>(p + 4);
    *reinterpret_cast<bf16x8*>(g_wb + (long)f * 8) = pack8(a, b);
}

// LDS layout (18432 B total -> 8 blocks/CU):
//   [0, 16384):      key tile, bf16 [16 rows][512], byte ^= (row&7)<<4
//   [16384, 18432):  h park (shared, written by wave 0) / later F partials
#define KOF 0
#define HOF 16384

__global__ __launch_bounds__(256, 8) void fused_free_energy(
    const float* __restrict__ key, const float* __restrict__ value,
    const float* __restrict__ b1, const float* __restrict__ b2,
    const float* __restrict__ pb,
    float* __restrict__ outF, float* __restrict__ outPred,
    float* __restrict__ outPrec, float* __restrict__ outErr)
{
    __shared__ __align__(16) char lds[18432];

    const bf16x8* W1F = reinterpret_cast<const bf16x8*>(g_wb);
    const bf16x8* W2F = reinterpret_cast<const bf16x8*>(g_wb + 32768);
    const bf16x8* WpF = reinterpret_cast<const bf16x8*>(g_wb + 65536);

    const int tid  = threadIdx.x;
    const int wave = tid >> 6;
    const int lane = tid & 63;
    const int lh   = lane & 15;
    const int lg   = lane >> 4;
    const long row0 = (long)blockIdx.x * BMR;
    const f32x4 zf = {0.f, 0.f, 0.f, 0.f};

    // ---- stage key tile (16 x 512) f32 -> bf16, swizzled ----
    #pragma unroll
    for (int i = 0; i < 4; ++i) {                // 1024 8-elem chunks / 256 thr
        int idx = i * 256 + tid;
        int r = idx >> 6, c8 = idx & 63;
        const float* p = key + (row0 + r) * DK + c8 * 8;
        float4 a = *reinterpret_cast<const float4*>(p);
        float4 b = *reinterpret_cast<const float4*>(p + 4);
        int byte = (r * 1024 + c8 * 16) ^ ((r & 7) << 4);
        *reinterpret_cast<bf16x8*>(lds + KOF + byte) = pack8(a, b);
    }
    __syncthreads();

    // key B-fragment from LDS: row lh, k-bytes kk*64 + lg*16
    #define KFRAG(kk) (*reinterpret_cast<const bf16x8*>( \
        lds + KOF + ((lh * 1024 + (kk) * 64 + lg * 16) ^ ((lh & 7) << 4))))

    // ---- GEMM1 (wave 0 only; h identical for all waves): h = gelu(key@W1^T + b1) ----
    if (wave == 0) {
        #pragma unroll
        for (int jt = 0; jt < 4; ++jt) {
            f32x4 aE = zf, aO = zf;
            #pragma unroll
            for (int kk = 0; kk < 16; kk += 2) {
                bf16x8 f0 = W1F[(jt * 16 + kk) * 64 + lane];
                bf16x8 f1 = W1F[(jt * 16 + kk + 1) * 64 + lane];
                aE = __builtin_amdgcn_mfma_f32_16x16x32_bf16(f0, KFRAG(kk),     aE, 0, 0, 0);
                aO = __builtin_amdgcn_mfma_f32_16x16x32_bf16(f1, KFRAG(kk + 1), aO, 0, 0, 0);
            }
            float4 b1v = *reinterpret_cast<const float4*>(b1 + jt * 16 + lg * 4);
            float b1a[4] = {b1v.x, b1v.y, b1v.z, b1v.w};
            short hs[4];
            #pragma unroll
            for (int r = 0; r < 4; ++r) {
                float z = aE[r] + aO[r] + b1a[r];
                float g = 0.5f * z * (1.0f + erff(z * 0.70710678f));  // exact GELU
                hs[r] = f2bf(g);
            }
            int hb = HOF + ((lh * 128 + jt * 32 + lg * 8) ^ ((lh & 7) << 4));
            short4 hv = {hs[0], hs[1], hs[2], hs[3]};
            *reinterpret_cast<short4*>(lds + hb) = hv;
        }
    }
    __syncthreads();
    bf16x8 hreg[2];
    #pragma unroll
    for (int kh = 0; kh < 2; ++kh) {
        int byte = (lh * 128 + kh * 64 + lg * 16) ^ ((lh & 7) << 4);
        hreg[kh] = *reinterpret_cast<const bf16x8*>(lds + HOF + byte);
    }
    __syncthreads();   // everyone has hreg; HOF may be reused for F partials later

    // ---- main loop: 8 col-tiles per wave, NO barriers, direct epilogue ----
    float facc = 0.f;
    const long grow = row0 + lh;                 // every wave covers the same 16 rows
    const float* vrow = value + grow * (long)DV;
    float* prow = outPred + grow * (long)DV;
    float* crow = outPrec + grow * (long)DV;
    float* erow = outErr  + grow * (long)DV;

    float4 vcur = *reinterpret_cast<const float4*>(vrow + wave * 128 + lg * 4);

    #pragma unroll 2
    for (int it = 0; it < 8; ++it) {
        const int tt = wave * 8 + it;            // global col-tile
        const int nb = tt * 16 + lg * 4;         // first f32 col this lane handles

        // prefetch next tile's value (clamped re-read on last iter)
        const int nbn = (it < 7) ? nb + 16 : nb;
        float4 vnx = *reinterpret_cast<const float4*>(vrow + nbn);

        // GEMM3: Wp frags coalesced from L2; two independent MFMA chains
        f32x4 aE = zf, aO = zf;
        #pragma unroll
        for (int kk = 0; kk < 16; kk += 2) {
            bf16x8 f0 = WpF[(tt * 16 + kk) * 64 + lane];
            bf16x8 f1 = WpF[(tt * 16 + kk + 1) * 64 + lane];
            aE = __builtin_amdgcn_mfma_f32_16x16x32_bf16(f0, KFRAG(kk),     aE, 0, 0, 0);
            aO = __builtin_amdgcn_mfma_f32_16x16x32_bf16(f1, KFRAG(kk + 1), aO, 0, 0, 0);
        }
        // GEMM2: W2 frags
        f32x4 acc2 = zf;
        #pragma unroll
        for (int kh = 0; kh < 2; ++kh) {
            bf16x8 f = W2F[(tt * 2 + kh) * 64 + lane];
            acc2 = __builtin_amdgcn_mfma_f32_16x16x32_bf16(f, hreg[kh], acc2, 0, 0, 0);
        }

        // epilogue: lane holds 4 consecutive cols (nb..nb+3) of row grow
        float4 b2v = *reinterpret_cast<const float4*>(b2 + nb);
        float4 pbv = *reinterpret_cast<const float4*>(pb + nb);
        float b2a[4] = {b2v.x, b2v.y, b2v.z, b2v.w};
        float pba[4] = {pbv.x, pbv.y, pbv.z, pbv.w};
        float va[4]  = {vcur.x, vcur.y, vcur.z, vcur.w};
        float prv[4], pcv[4], erv[4];
        #pragma unroll
        for (int r = 0; r < 4; ++r) {
            float z    = aE[r] + aO[r] + pba[r];         // prec-head logit
            float pred = acc2[r] + b2a[r];
            float prec = fmaxf(z, 0.f) + __logf(1.0f + __expf(-fabsf(z))) + 0.01f;
            float err  = fminf(fmaxf(va[r] - pred, -3.f), 3.f);
            prv[r] = pred; pcv[r] = prec; erv[r] = err;
            facc += prec * err * err - __logf(prec);
        }
        float4 pr4 = {prv[0], prv[1], prv[2], prv[3]};
        float4 pc4 = {pcv[0], pcv[1], pcv[2], pcv[3]};
        float4 er4 = {erv[0], erv[1], erv[2], erv[3]};
        *reinterpret_cast<float4*>(prow + nb) = pr4;
        *reinterpret_cast<float4*>(crow + nb) = pc4;
        *reinterpret_cast<float4*>(erow + nb) = er4;

        vcur = vnx;
    }

    // ---- F: reduce over lg within wave, then across waves via LDS ----
    facc += __shfl_xor(facc, 16, 64);
    facc += __shfl_xor(facc, 32, 64);            // lanes 0..15 now hold row sums
    float* fpart = reinterpret_cast<float*>(lds + HOF);
    if (lane < 16) fpart[wave * 16 + lane] = facc;
    __syncthreads();
    if (tid < 16) {
        float s = fpart[tid] + fpart[16 + tid] + fpart[32 + tid] + fpart[48 + tid];
        outF[row0 + tid] = s * (1.0f / 512.0f);
    }
}

extern "C" void kernel_launch(void* const* d_in, const int* in_sizes, int n_in,
                              void* d_out, int out_size, void* d_ws, size_t ws_size,
                              hipStream_t stream) {
    const float* key   = (const float*)d_in[0];
    const float* value = (const float*)d_in[1];
    const float* W1    = (const float*)d_in[2];
    const float* b1    = (const float*)d_in[3];
    const float* W2    = (const float*)d_in[4];
    const float* b2    = (const float*)d_in[5];
    const float* Wp    = (const float*)d_in[6];
    const float* pb    = (const float*)d_in[7];

    float* outF    = (float*)d_out;
    float* outPred = outF + BATCH;
    float* outPrec = outPred + (long)BATCH * DV;
    float* outErr  = outPrec + (long)BATCH * DV;

    conv_weights<<<160, 256, 0, stream>>>(W1, W2, Wp);
    fused_free_energy<<<BATCH / BMR, 256, 0, stream>>>(key, value, b1, b2, pb,
                                                       outF, outPred, outPrec, outErr);
}

// Round 15
// 343.976 us; speedup vs baseline: 2.2144x; 2.2144x over previous
//
#include <hip/hip_runtime.h>
#include <hip/hip_bf16.h>

#define BATCH 65536
#define DK 512
#define DV 512
#define DH 64
#define BMR 16          // rows per block

typedef __attribute__((ext_vector_type(8))) short bf16x8;
typedef __attribute__((ext_vector_type(4))) float f32x4;

// raw barrier pair: drain LDS ops (write->read visibility), do NOT drain vmcnt
#define LGKM_BAR() do { asm volatile("s_waitcnt lgkmcnt(0)" ::: "memory"); \
                        __builtin_amdgcn_s_barrier(); } while (0)
#define BAR()      do { asm volatile("" ::: "memory"); \
                        __builtin_amdgcn_s_barrier(); } while (0)

// FRAGMENT-ORDERED bf16 weight images (one coalesced 1KB load per wave-frag):
//   shorts [0, 32768):       W1F  (4 tiles x 16 kk x 64 lanes x 8)
//   shorts [32768, 65536):   W2F  (32 tiles x 2 kh x 64 lanes x 8)
//   shorts [65536, 327680):  WpF  (32 tiles x 16 kk x 64 lanes x 8)
__device__ __align__(16) short g_wb[327680];

__device__ __forceinline__ short f2bf(float f) {
    union { __hip_bfloat16 h; short s; } u;
    u.h = __float2bfloat16(f);
    return u.s;
}

__device__ __forceinline__ bf16x8 pack8(float4 a, float4 b) {
    bf16x8 r;
    r[0] = f2bf(a.x); r[1] = f2bf(a.y); r[2] = f2bf(a.z); r[3] = f2bf(a.w);
    r[4] = f2bf(b.x); r[5] = f2bf(b.y); r[6] = f2bf(b.z); r[7] = f2bf(b.w);
    return r;
}

__global__ __launch_bounds__(256) void conv_weights(
    const float* __restrict__ W1, const float* __restrict__ W2,
    const float* __restrict__ Wp)
{
    int f = blockIdx.x * 256 + threadIdx.x;
    int lane = f & 63;
    const float* src; int stride, row, col;
    if (f < 4096) {                    // W1F
        int t = f >> 10, kk = (f >> 6) & 15;
        src = W1; stride = DK;
        row = t * 16 + (lane & 15); col = kk * 32 + (lane >> 4) * 8;
    } else if (f < 8192) {             // W2F
        int g = f - 4096; int t = g >> 7, kh = (g >> 6) & 1;
        src = W2; stride = DH;
        row = t * 16 + (lane & 15); col = kh * 32 + (lane >> 4) * 8;
    } else {                           // WpF
        int g = f - 8192; int t = g >> 10, kk = (g >> 6) & 15;
        src = Wp; stride = DK;
        row = t * 16 + (lane & 15); col = kk * 32 + (lane >> 4) * 8;
    }
    const float* p = src + (long)row * stride + col;
    float4 a = *reinterpret_cast<const float4*>(p);
    float4 b = *reinterpret_cast<const float4*>(p + 4);
    *reinterpret_cast<bf16x8*>(g_wb + (long)f * 8) = pack8(a, b);
}

// LDS layout (32 KB total -> 5 blocks/CU):
//   [0, 16384):      key tile, bf16 [16 rows][512], byte ^= (row&7)<<4
//   [16384, 24576):  XP: pred stage f32 [16][128] (also hpark before main loop)
//   [24576, 32768):  XZ: z3 stage f32 [16][128]
#define KOF 0
#define XP  16384
#define XZ  24576

__global__ __launch_bounds__(256, 5) void fused_free_energy(
    const float* __restrict__ key, const float* __restrict__ value,
    const float* __restrict__ b1, const float* __restrict__ b2,
    const float* __restrict__ pb,
    float* __restrict__ outF, float* __restrict__ outPred,
    float* __restrict__ outPrec, float* __restrict__ outErr)
{
    __shared__ __align__(16) char lds[32768];

    const bf16x8* W1F = reinterpret_cast<const bf16x8*>(g_wb);
    const bf16x8* W2F = reinterpret_cast<const bf16x8*>(g_wb + 32768);
    const bf16x8* WpF = reinterpret_cast<const bf16x8*>(g_wb + 65536);

    const int tid  = threadIdx.x;
    const int wave = tid >> 6;
    const int lane = tid & 63;
    const int lh   = lane & 15;
    const int lg   = lane >> 4;
    const long row0 = (long)blockIdx.x * BMR;
    const f32x4 zf = {0.f, 0.f, 0.f, 0.f};

    // writeback geometry (thread-constant)
    const int rowA  = wave * 4 + (lane >> 5);        // first of 2 rows (other +2)
    const int colw  = (lane & 31) * 4;               // f32 col within 128-col segment
    const float* vbase0 = value + (row0 + rowA) * (long)DV + colw;
    const float* vbase1 = vbase0 + 2 * DV;

    float4 vA0, vA1, vB0, vB1;                       // value prefetch double-buffer
#define PREF(p, d0, d1) do { \
        d0 = *reinterpret_cast<const float4*>(vbase0 + (p) * 128); \
        d1 = *reinterpret_cast<const float4*>(vbase1 + (p) * 128); } while (0)

    PREF(0, vA0, vA1);                               // phase-0 value in flight

    // ---- stage key tile (16 x 512) f32 -> bf16, swizzled ----
    {
        #pragma unroll
        for (int i = 0; i < 4; ++i) {            // 1024 8-elem chunks / 256 thr
            int idx = i * 256 + tid;
            int r = idx >> 6, c8 = idx & 63;
            const float* p = key + (row0 + r) * DK + c8 * 8;
            float4 a = *reinterpret_cast<const float4*>(p);
            float4 b = *reinterpret_cast<const float4*>(p + 4);
            int byte = (r * 1024 + c8 * 16) ^ ((r & 7) << 4);
            *reinterpret_cast<bf16x8*>(lds + KOF + byte) = pack8(a, b);
        }
    }
    LGKM_BAR();

    // key B-fragment from LDS: row lh, k-offset kk*32 + lg*8 (bytes kk*64+lg*16)
    #define KFRAG(kk) (*reinterpret_cast<const bf16x8*>( \
        lds + KOF + ((lh * 1024 + (kk) * 64 + lg * 16) ^ ((lh & 7) << 4))))

    // ---- GEMM1 (wave 0 only; h identical across waves): h = gelu(key@W1^T+b1) ----
    bf16x8 hreg[2];
    {
        if (wave == 0) {
            #pragma unroll
            for (int jt = 0; jt < 4; ++jt) {
                f32x4 aE = zf, aO = zf;
                #pragma unroll
                for (int kk = 0; kk < 16; kk += 2) {
                    bf16x8 f0 = W1F[(jt * 16 + kk) * 64 + lane];
                    bf16x8 f1 = W1F[(jt * 16 + kk + 1) * 64 + lane];
                    aE = __builtin_amdgcn_mfma_f32_16x16x32_bf16(f0, KFRAG(kk),     aE, 0, 0, 0);
                    aO = __builtin_amdgcn_mfma_f32_16x16x32_bf16(f1, KFRAG(kk + 1), aO, 0, 0, 0);
                }
                float4 b1v = *reinterpret_cast<const float4*>(b1 + jt * 16 + lg * 4);
                float b1a[4] = {b1v.x, b1v.y, b1v.z, b1v.w};
                short hs[4];
                #pragma unroll
                for (int r = 0; r < 4; ++r) {
                    float z = aE[r] + aO[r] + b1a[r];
                    float g = 0.5f * z * (1.0f + erff(z * 0.70710678f));  // exact GELU
                    hs[r] = f2bf(g);
                }
                int hb = XP + ((lh * 128 + jt * 32 + lg * 8) ^ ((lh & 7) << 4));
                short4 hv = {hs[0], hs[1], hs[2], hs[3]};
                *reinterpret_cast<short4*>(lds + hb) = hv;
            }
        }
        LGKM_BAR();
        #pragma unroll
        for (int kh = 0; kh < 2; ++kh) {
            int byte = (lh * 128 + kh * 64 + lg * 16) ^ ((lh & 7) << 4);
            hreg[kh] = *reinterpret_cast<const bf16x8*>(lds + XP + byte);
        }
        LGKM_BAR();   // own reads drained; XP free for staging
    }

    float facc0 = 0.f, facc1 = 0.f;

    // ---- one phase: compute 2 col-tiles -> LDS stage -> stream 128-col rows ----
#define COMPUTE(ot) do {                                                          \
        _Pragma("unroll")                                                         \
        for (int sub = 0; sub < 2; ++sub) {                                       \
            const int tt = (ot) * 8 + wave * 2 + sub;                             \
            f32x4 aE = zf, aO = zf;                                               \
            _Pragma("unroll")                                                     \
            for (int kk = 0; kk < 16; kk += 2) {                                  \
                bf16x8 f0 = WpF[(tt * 16 + kk) * 64 + lane];                      \
                bf16x8 f1 = WpF[(tt * 16 + kk + 1) * 64 + lane];                  \
                aE = __builtin_amdgcn_mfma_f32_16x16x32_bf16(f0, KFRAG(kk),     aE, 0, 0, 0); \
                aO = __builtin_amdgcn_mfma_f32_16x16x32_bf16(f1, KFRAG(kk + 1), aO, 0, 0, 0); \
            }                                                                     \
            f32x4 acc2 = zf;                                                      \
            _Pragma("unroll")                                                     \
            for (int kh = 0; kh < 2; ++kh) {                                      \
                bf16x8 f = W2F[(tt * 2 + kh) * 64 + lane];                        \
                acc2 = __builtin_amdgcn_mfma_f32_16x16x32_bf16(f, hreg[kh], acc2, 0, 0, 0); \
            }                                                                     \
            int nb = tt * 16 + lg * 4;                                            \
            float4 b2v = *reinterpret_cast<const float4*>(b2 + nb);               \
            float4 pbv = *reinterpret_cast<const float4*>(pb + nb);               \
            f32x4 pz, zz;                                                         \
            pz[0] = acc2[0] + b2v.x; pz[1] = acc2[1] + b2v.y;                     \
            pz[2] = acc2[2] + b2v.z; pz[3] = acc2[3] + b2v.w;                     \
            zz[0] = aE[0] + aO[0] + pbv.x; zz[1] = aE[1] + aO[1] + pbv.y;         \
            zz[2] = aE[2] + aO[2] + pbv.z; zz[3] = aE[3] + aO[3] + pbv.w;         \
            int relb = (wave * 2 + sub) * 64 + lg * 16;                           \
            int sb = (lh * 512 + relb) ^ ((lh & 7) << 4);                         \
            *reinterpret_cast<f32x4*>(lds + XP + sb) = pz;                        \
            *reinterpret_cast<f32x4*>(lds + XZ + sb) = zz;                        \
        }                                                                         \
    } while (0)

#define WRITEBACK(ot, v0, v1) do {                                                \
        _Pragma("unroll")                                                         \
        for (int ch = 0; ch < 2; ++ch) {                                          \
            int row  = rowA + ch * 2;                                             \
            int colb = (lane & 31) * 16;                                          \
            int rb   = (row * 512 + colb) ^ ((row & 7) << 4);                     \
            float4 pr = *reinterpret_cast<const float4*>(lds + XP + rb);          \
            float4 zv = *reinterpret_cast<const float4*>(lds + XZ + rb);          \
            long ga = (row0 + row) * (long)DV + (ot) * 128 + colw;                \
            float4 va = (ch == 0) ? (v0) : (v1);                                  \
            float pa[4]  = {pr.x, pr.y, pr.z, pr.w};                              \
            float za[4]  = {zv.x, zv.y, zv.z, zv.w};                              \
            float vaa[4] = {va.x, va.y, va.z, va.w};                              \
            float er[4], pc[4], f = 0.f;                                          \
            _Pragma("unroll")                                                     \
            for (int r = 0; r < 4; ++r) {                                         \
                float z = za[r];                                                  \
                float prec = fmaxf(z, 0.f) + __logf(1.0f + __expf(-fabsf(z))) + 0.01f; \
                float e = fminf(fmaxf(vaa[r] - pa[r], -3.f), 3.f);                \
                pc[r] = prec; er[r] = e;                                          \
                f += prec * e * e - __logf(prec);                                 \
            }                                                                     \
            float4 pc4 = {pc[0], pc[1], pc[2], pc[3]};                            \
            float4 er4 = {er[0], er[1], er[2], er[3]};                            \
            *reinterpret_cast<float4*>(outPred + ga) = pr;                        \
            *reinterpret_cast<float4*>(outPrec + ga) = pc4;                       \
            *reinterpret_cast<float4*>(outErr  + ga) = er4;                       \
            if (ch == 0) facc0 += f; else facc1 += f;                             \
        }                                                                         \
    } while (0)

    // ---- 4 phases, fully unrolled; value double-buffer alternates A/B ----
    COMPUTE(0); PREF(1, vB0, vB1); LGKM_BAR();
    WRITEBACK(0, vA0, vA1); BAR();

    COMPUTE(1); PREF(2, vA0, vA1); LGKM_BAR();
    WRITEBACK(1, vB0, vB1); BAR();

    COMPUTE(2); PREF(3, vB0, vB1); LGKM_BAR();
    WRITEBACK(2, vA0, vA1); BAR();

    COMPUTE(3); LGKM_BAR();
    WRITEBACK(3, vB0, vB1);

    // ---- F: reduce across the 32-lane group sharing a row ----
    #pragma unroll
    for (int ch = 0; ch < 2; ++ch) {
        float s = (ch == 0) ? facc0 : facc1;
        #pragma unroll
        for (int off = 1; off < 32; off <<= 1)
            s += __shfl_xor(s, off, 64);
        if ((lane & 31) == 0)
            outF[row0 + rowA + ch * 2] = s * (1.0f / 512.0f);
    }
}

extern "C" void kernel_launch(void* const* d_in, const int* in_sizes, int n_in,
                              void* d_out, int out_size, void* d_ws, size_t ws_size,
                              hipStream_t stream) {
    const float* key   = (const float*)d_in[0];
    const float* value = (const float*)d_in[1];
    const float* W1    = (const float*)d_in[2];
    const float* b1    = (const float*)d_in[3];
    const float* W2    = (const float*)d_in[4];
    const float* b2    = (const float*)d_in[5];
    const float* Wp    = (const float*)d_in[6];
    const float* pb    = (const float*)d_in[7];

    float* outF    = (float*)d_out;
    float* outPred = outF + BATCH;
    float* outPrec = outPred + (long)BATCH * DV;
    float* outErr  = outPrec + (long)BATCH * DV;

    conv_weights<<<160, 256, 0, stream>>>(W1, W2, Wp);
    fused_free_energy<<<BATCH / BMR, 256, 0, stream>>>(key, value, b1, b2, pb,
                                                       outF, outPred, outPrec, outErr);
}